// Round 10
// baseline (69.465 us; speedup 1.0000x reference)
//
#include <hip/hip_runtime.h>
#include <hip/hip_bf16.h>

#define NUM_GT 25
#define NUM_PRED 40
#define GRID 2048
#define BLOCK 256
#define CHUNK 512            // voxels per block-iteration (8/lane x 64 lanes)

// ws layout (u32 words):
//   [r*65 + s], r=0..63 : partial SAD sums; sbin s: 0..24 = g_gt(s),
//                         25..64 = g_pr(s-25)
//   [4160 + p], p=0..40 : overlap bitmask row p
#define WS_OV    4160
#define WS_WORDS (4160 + 41)

__device__ __forceinline__ unsigned pack_i4(int4 v) {
    return (unsigned)v.x | ((unsigned)v.y << 8) |
           ((unsigned)v.z << 16) | ((unsigned)v.w << 24);
}
__device__ __forceinline__ unsigned pack_f4(float4 v) {
    return (unsigned)v.x | ((unsigned)v.y << 8) |
           ((unsigned)v.z << 16) | ((unsigned)v.w << 24);
}

#define SAD(A, W, K) asm("v_sad_u8 %0, %1, %2, %0" : "+v"(A) : "v"(W), "s"(K))

template <int NB>
__device__ __forceinline__ void reduce_flush(
    unsigned* acc, int sbin0, int lane, unsigned* __restrict__ ws, int row)
{
    #pragma unroll
    for (int j = 0; j < NB; ++j) {
        unsigned c = acc[j];
        c += __shfl_down(c, 32, 64);
        c += __shfl_down(c, 16, 64);
        c += __shfl_down(c, 8, 64);
        c += __shfl_down(c, 4, 64);
        c += __shfl_down(c, 2, 64);
        c += __shfl_down(c, 1, 64);
        if (lane == 0 && c) atomicAdd(&ws[row * 65 + sbin0 + j], c);
    }
}

// gt-only wave: NB bins starting at gt label kb0 (sbin == kb0 + j)
template <int NB>
__device__ __forceinline__ void scan_gt(
    const int4* __restrict__ g4, int kb0, int nchunks, int lane,
    unsigned* __restrict__ ws, int row)
{
    unsigned acc[NB];
    #pragma unroll
    for (int j = 0; j < NB; ++j) acc[j] = 0u;

    for (int c = blockIdx.x; c < nchunks; c += GRID) {
        const int q = c * (CHUNK / 4) + lane * 2;
        int4 a = g4[q], b = g4[q + 1];
        unsigned GA = pack_i4(a), GB = pack_i4(b);
        #pragma unroll
        for (int j = 0; j < NB; ++j) {
            const unsigned K = (unsigned)((kb0 + j) * 0x01010101u);
            SAD(acc[j], GA, K);
            SAD(acc[j], GB, K);
        }
    }
    reduce_flush<NB>(acc, kb0, lane, ws, row);
}

// pred-only wave: NB bins starting at pred label kb0 (sbin == 25 + kb0 + j)
template <int NB>
__device__ __forceinline__ void scan_pr(
    const float4* __restrict__ p4, int kb0, int nchunks, int lane,
    unsigned* __restrict__ ws, int row)
{
    unsigned acc[NB];
    #pragma unroll
    for (int j = 0; j < NB; ++j) acc[j] = 0u;

    for (int c = blockIdx.x; c < nchunks; c += GRID) {
        const int q = c * (CHUNK / 4) + lane * 2;
        float4 a = p4[q], b = p4[q + 1];
        unsigned PA = pack_f4(a), PB = pack_f4(b);
        #pragma unroll
        for (int j = 0; j < NB; ++j) {
            const unsigned K = (unsigned)((kb0 + j) * 0x01010101u);
            SAD(acc[j], PA, K);
            SAD(acc[j], PB, K);
        }
    }
    reduce_flush<NB>(acc, 25 + kb0, lane, ws, row);
}

// wave 0: gt bins 0..12 + overlap matrix (reads both arrays)
__device__ __forceinline__ void scan_mixed(
    const float4* __restrict__ p4, const int4* __restrict__ g4,
    int nchunks, int lane, unsigned* __restrict__ ws, int row,
    unsigned* sovl)
{
    unsigned acc[13];
    #pragma unroll
    for (int j = 0; j < 13; ++j) acc[j] = 0u;

    for (int c = blockIdx.x; c < nchunks; c += GRID) {
        const int q = c * (CHUNK / 4) + lane * 2;
        int4  ga = g4[q], gb = g4[q + 1];
        float4 pa = p4[q], pb = p4[q + 1];

        unsigned a0 = (unsigned)ga.x, a1 = (unsigned)ga.y;
        unsigned a2 = (unsigned)ga.z, a3 = (unsigned)ga.w;
        unsigned a4 = (unsigned)gb.x, a5 = (unsigned)gb.y;
        unsigned a6 = (unsigned)gb.z, a7 = (unsigned)gb.w;
        unsigned b0 = (unsigned)pa.x, b1 = (unsigned)pa.y;
        unsigned b2 = (unsigned)pa.z, b3 = (unsigned)pa.w;
        unsigned b4 = (unsigned)pb.x, b5 = (unsigned)pb.y;
        unsigned b6 = (unsigned)pb.z, b7 = (unsigned)pb.w;

        unsigned ok = (sovl[b0 & 63] >> (a0 & 31)) & (sovl[b1 & 63] >> (a1 & 31))
                    & (sovl[b2 & 63] >> (a2 & 31)) & (sovl[b3 & 63] >> (a3 & 31))
                    & (sovl[b4 & 63] >> (a4 & 31)) & (sovl[b5 & 63] >> (a5 & 31))
                    & (sovl[b6 & 63] >> (a6 & 31)) & (sovl[b7 & 63] >> (a7 & 31));
        if (!(ok & 1u)) {                    // rare after warm-up
            atomicOr(&sovl[b0 & 63], 1u << (a0 & 31));
            atomicOr(&sovl[b1 & 63], 1u << (a1 & 31));
            atomicOr(&sovl[b2 & 63], 1u << (a2 & 31));
            atomicOr(&sovl[b3 & 63], 1u << (a3 & 31));
            atomicOr(&sovl[b4 & 63], 1u << (a4 & 31));
            atomicOr(&sovl[b5 & 63], 1u << (a5 & 31));
            atomicOr(&sovl[b6 & 63], 1u << (a6 & 31));
            atomicOr(&sovl[b7 & 63], 1u << (a7 & 31));
        }

        unsigned GA = a0 | (a1 << 8) | (a2 << 16) | (a3 << 24);
        unsigned GB = a4 | (a5 << 8) | (a6 << 16) | (a7 << 24);
        #pragma unroll
        for (int j = 0; j < 13; ++j) {
            const unsigned K = (unsigned)(j * 0x01010101u);
            SAD(acc[j], GA, K);
            SAD(acc[j], GB, K);
        }
    }
    reduce_flush<13>(acc, 0, lane, ws, row);

    if (lane < 41) {
        unsigned v = sovl[lane];
        if (v) atomicOr(&ws[WS_OV + lane], v);
    }
}

// ---------------------------------------------------------------------------
// Histogram: bins split across the 4 waves (13/12 gt, 20/20 pred), each wave
// streams its array directly from global. No barriers, no LDS in the hot
// loop; <=20 accumulators/wave keeps everything in arch VGPRs (R9 evidence).
// ---------------------------------------------------------------------------
__global__ __launch_bounds__(BLOCK) void hist_kernel(
    const float* __restrict__ pred, const int* __restrict__ gt,
    unsigned* __restrict__ ws, int n)
{
    __shared__ unsigned sovl[64];
    const int tid  = threadIdx.x;
    const int lane = tid & 63;
    const int wave = tid >> 6;

    if (tid < 64) sovl[tid] = 0u;
    __syncthreads();

    const int nchunks = n / CHUNK;
    const int row = blockIdx.x & 63;
    const float4* __restrict__ p4 = (const float4*)pred;
    const int4* __restrict__  g4 = (const int4*)gt;

    if      (wave == 0) scan_mixed(p4, g4, nchunks, lane, ws, row, sovl);
    else if (wave == 1) scan_gt<12>(g4, 13, nchunks, lane, ws, row);
    else if (wave == 2) scan_pr<20>(p4, 0, nchunks, lane, ws, row);
    else                scan_pr<20>(p4, 20, nchunks, lane, ws, row);

    // remainder voxels (n % CHUNK; none for 256^3) — defensive
    if (blockIdx.x == 0 && tid == 0) {
        for (int v = nchunks * CHUNK; v < n; ++v) {
            int p = (int)pred[v];
            int g = gt[v];
            for (int b = 0; b < 25; ++b) atomicAdd(&ws[b], (unsigned)abs(g - b));
            for (int b = 0; b < 40; ++b) atomicAdd(&ws[25 + b], (unsigned)abs(p - b));
            atomicOr(&ws[WS_OV + min(max(p, 0), NUM_PRED)], 1u << (g & 31));
        }
    }
}

// ---------------------------------------------------------------------------
// Finisher: sum 64 partial rows, exact second-difference counts (int64) +
// fp64 dice (proven absmax = 0, rounds 6-9).
// ---------------------------------------------------------------------------
__global__ __launch_bounds__(128) void finish_kernel(
    const unsigned* __restrict__ ws, float* __restrict__ out, int n)
{
    __shared__ long long gsum[65];
    __shared__ long long psz[41];
    __shared__ unsigned ovs[41];
    const int t = threadIdx.x;

    if (t < 65) {
        unsigned s = 0;
        for (int r = 0; r < 64; ++r) s += ws[r * 65 + t];
        gsum[t] = (long long)s;
    }
    if (t < 41) ovs[t] = ws[WS_OV + t];
    __syncthreads();

    const long long N = n;
    if (t < 41) {                            // pred_sizes[P], P = t
        const long long Sp = gsum[25];
        int P = t;
        long long f;
        if (P == 0)       f = (N - gsum[25 + 0] + gsum[25 + 1]) / 2;
        else if (P <= 38) f = (gsum[25 + P - 1] - 2 * gsum[25 + P] + gsum[25 + P + 1]) / 2;
        else if (P == 39) f = (gsum[25 + 38] - 2 * gsum[25 + 39] + (40 * N - Sp)) / 2;
        else              f = (gsum[25 + 39] - 39 * N + Sp) / 2;   // P = 40
        psz[P] = f;
    }
    __syncthreads();

    if (t < 64) {
        const int lane = t;
        const long long Sg = gsum[0];
        double dice = 0.0;
        int present = 0;
        if (lane < 25) {                     // gt component label L = lane+1
            int L = lane + 1;
            long long gs;
            if (L <= 23)      gs = (gsum[L - 1] - 2 * gsum[L] + gsum[L + 1]) / 2;
            else if (L == 24) gs = (gsum[23] - 2 * gsum[24] + (25 * N - Sg)) / 2;
            else              gs = (gsum[24] - 24 * N + Sg) / 2;   // L = 25
            if (gs > 0) {
                present = 1;
                double un = 0.0;
                const unsigned bit = 1u << L;
                for (int p = 0; p < 41; ++p)
                    if (ovs[p] & bit) un += (double)psz[p];
                dice = 2.0 * (double)gs / (un + (double)gs + 1.0);
            }
        }
        int fp = 0;
        if (lane < 41) {
            if (psz[lane] > 0 && (ovs[lane] & 0x3FFFFFEu) == 0) fp = 1;
        }

        int num_gt = __popcll(__ballot(present != 0));
        int nfp    = __popcll(__ballot(fp != 0));
        #pragma unroll
        for (int o = 32; o >= 1; o >>= 1) dice += __shfl_xor(dice, o, 64);

        if (lane == 0) out[0] = (float)(dice / (double)(num_gt + nfp));
    }
}

extern "C" void kernel_launch(void* const* d_in, const int* in_sizes, int n_in,
                              void* d_out, int out_size, void* d_ws, size_t ws_size,
                              hipStream_t stream) {
    const float* pred = (const float*)d_in[0];
    const int* gt = (const int*)d_in[1];
    float* out = (float*)d_out;
    unsigned* ws = (unsigned*)d_ws;
    const int n = in_sizes[0];

    hipMemsetAsync(ws, 0, WS_WORDS * sizeof(unsigned), stream);

    hist_kernel<<<GRID, BLOCK, 0, stream>>>(pred, gt, ws, n);
    finish_kernel<<<1, 128, 0, stream>>>(ws, out, n);
}